// Round 4
// baseline (1191.726 us; speedup 1.0000x reference)
//
#include <hip/hip_runtime.h>

#define D 64
#define NPB_SHIFT 9                    // 512 dst nodes per bucket
#define NPB (1 << NPB_SHIFT)
#define NB 196                         // ceil(100000/512) = 196
#define NSLICE 8                       // one slice per XCD (blockIdx & 7)
#define GRID_SCAT 1024                 // MUST be identical for bkt_hist / bkt_scatter

// ---------- K1: per-(etype,bucket,slice) histogram, LDS-aggregated ----------
__global__ __launch_bounds__(256) void bkt_hist(
    const int* __restrict__ d0, const int* __restrict__ d1, const int* __restrict__ d2,
    int* __restrict__ hist, int nE)    // hist[et][b][s]
{
    const int et = blockIdx.y;
    const int* dst = et == 0 ? d0 : (et == 1 ? d1 : d2);
    __shared__ int h[NB];
    for (int i = threadIdx.x; i < NB; i += 256) h[i] = 0;
    __syncthreads();
    for (int e = blockIdx.x * 256 + threadIdx.x; e < nE; e += GRID_SCAT * 256)
        atomicAdd(&h[dst[e] >> NPB_SHIFT], 1);
    __syncthreads();
    const int s = blockIdx.x & (NSLICE - 1);
    int* gh = hist + et * NB * NSLICE;
    for (int i = threadIdx.x; i < NB; i += 256)
        if (h[i]) atomicAdd(&gh[i * NSLICE + s], h[i]);
}

// ---------- K2: exclusive scan of hist[et] (NB*NSLICE each), bucket-major ----------
__global__ __launch_bounds__(256) void bkt_scan(
    const int* __restrict__ hist, int* __restrict__ off, int* __restrict__ cur)
{
    const int et = blockIdx.x;
    const int M = NB * NSLICE;
    const int* h = hist + et * M;
    int* o = off + et * M;
    int* c = cur + et * M;
    __shared__ int carry;
    __shared__ int wsum[4];
    if (threadIdx.x == 0) carry = 0;
    __syncthreads();
    for (int base = 0; base < M; base += 256) {
        const int tid = threadIdx.x;
        const int v = (base + tid < M) ? h[base + tid] : 0;
        int inc = v;
#pragma unroll
        for (int of = 1; of < 64; of <<= 1) {
            int t = __shfl_up(inc, of);
            if ((tid & 63) >= of) inc += t;
        }
        if ((tid & 63) == 63) wsum[tid >> 6] = inc;
        __syncthreads();
        int woff = 0;
        for (int i = 0; i < (tid >> 6); ++i) woff += wsum[i];
        const int excl = carry + woff + inc - v;
        if (base + tid < M) { o[base + tid] = excl; c[base + tid] = excl; }
        __syncthreads();
        if (tid == 255) carry = excl + v;
        __syncthreads();
    }
}

// ---------- K3: scatter packed edges into bucket regions (slice-local frontiers) ----------
__global__ __launch_bounds__(256) void bkt_scatter(
    const int* __restrict__ s0, const int* __restrict__ d0,
    const int* __restrict__ s1, const int* __restrict__ d1,
    const int* __restrict__ s2, const int* __restrict__ d2,
    int* __restrict__ cur, int* __restrict__ bkt, int nE, int E)
{
    const int et = blockIdx.y;
    const int* src = et == 0 ? s0 : (et == 1 ? s1 : s2);
    const int* dst = et == 0 ? d0 : (et == 1 ? d1 : d2);
    int* c = cur + et * NB * NSLICE;
    int* bk = bkt + (size_t)et * E;
    const int s = blockIdx.x & (NSLICE - 1);
    for (int e = blockIdx.x * 256 + threadIdx.x; e < nE; e += GRID_SCAT * 256) {
        const int dd = dst[e];
        const int b = dd >> NPB_SHIFT;
        const int pos = atomicAdd(&c[b * NSLICE + s], 1);
        bk[pos] = src[e] | ((dd & (NPB - 1)) << 17);   // src < 2^17, dl < 2^9
    }
}

// ---------- K4: per-bucket CSR finalize: hist -> scan -> place; emits cnt/rp/lst ----------
__global__ __launch_bounds__(256) void bkt_csr(
    const int* __restrict__ off, const int* __restrict__ bkt_all,
    int* __restrict__ rp_all, int* __restrict__ cnt_all, int* __restrict__ lst_all,
    int N, int E)
{
    const int et = blockIdx.y;
    const int b = blockIdx.x;
    const int* o = off + et * NB * NSLICE;
    const int* bk = bkt_all + (size_t)et * E;
    int* lst = lst_all + (size_t)et * E;
    int* rp  = rp_all  + (size_t)et * N;
    int* cnt = cnt_all + (size_t)et * N;
    const int A  = o[b * NSLICE];
    const int Bb = (b + 1 < NB) ? o[(b + 1) * NSLICE] : E;

    __shared__ int h[NPB];
    __shared__ int cu[NPB];
    __shared__ int ws2[4];
    for (int i = threadIdx.x; i < NPB; i += 256) h[i] = 0;
    __syncthreads();
    for (int i = A + threadIdx.x; i < Bb; i += 256)
        atomicAdd(&h[((unsigned)bk[i]) >> 17], 1);
    __syncthreads();

    // exclusive scan of NPB=512 counters, 2 per thread
    const int tid = threadIdx.x;
    const int v0 = h[2 * tid], v1 = h[2 * tid + 1];
    const int tsum = v0 + v1;
    int inc = tsum;
#pragma unroll
    for (int of = 1; of < 64; of <<= 1) {
        int t = __shfl_up(inc, of);
        if ((tid & 63) >= of) inc += t;
    }
    if ((tid & 63) == 63) ws2[tid >> 6] = inc;
    __syncthreads();
    int woff = 0;
    for (int i = 0; i < (tid >> 6); ++i) woff += ws2[i];
    const int excl = woff + inc - tsum;
    cu[2 * tid] = excl;
    cu[2 * tid + 1] = excl + v0;
    const int n0 = b << NPB_SHIFT;
    if (n0 + 2 * tid < N)     { cnt[n0 + 2 * tid]     = v0; rp[n0 + 2 * tid]     = A + excl; }
    if (n0 + 2 * tid + 1 < N) { cnt[n0 + 2 * tid + 1] = v1; rp[n0 + 2 * tid + 1] = A + excl + v0; }
    __syncthreads();

    for (int i = A + threadIdx.x; i < Bb; i += 256) {
        const int w = bk[i];
        const int dl = ((unsigned)w) >> 17;
        const int pos = atomicAdd(&cu[dl], 1);
        lst[A + pos] = w & 0x1FFFF;
    }
}

// ---------- K5: per-dst gather + mean + fused projection (unchanged from R3) ----------
template <bool RMW>
__global__ __launch_bounds__(256) void gather_proj(
    const float* __restrict__ feat, const int* __restrict__ rp,
    const int* __restrict__ cnt, const int* __restrict__ lst,
    const float* __restrict__ W, const float* __restrict__ bias,
    float* __restrict__ out, int N)
{
    __shared__ float WT[64][65];
    __shared__ float bs[64];
    for (int i = threadIdx.x; i < 4096; i += 256)
        WT[i & 63][i >> 6] = W[i];
    if (threadIdx.x < 64) bs[threadIdx.x] = bias[threadIdx.x];
    __syncthreads();

    const int lane = threadIdx.x & 63;
    const int n = blockIdx.x * 4 + (threadIdx.x >> 6);
    if (n >= N) return;

    const int deg = cnt[n];
    const int start = rp[n];
    float s0 = 0.0f, s1 = 0.0f;
    for (int base = 0; base < deg; base += 8) {
        int idx[8];
        float f[8];
#pragma unroll
        for (int j = 0; j < 8; ++j)
            idx[j] = (base + j < deg) ? lst[start + base + j] : -1;
#pragma unroll
        for (int j = 0; j < 8; ++j)
            f[j] = feat[(idx[j] < 0 ? 0 : idx[j]) * D + lane];
#pragma unroll
        for (int j = 0; j < 8; ++j) {
            const float v = idx[j] < 0 ? 0.0f : f[j];
            if (j & 1) s1 += v; else s0 += v;
        }
    }
    const float m = deg > 0 ? (s0 + s1) / (float)deg : 0.0f;

    float a0 = deg > 0 ? bs[lane] : 0.0f;
    float a1 = 0.0f, a2 = 0.0f, a3 = 0.0f;
#pragma unroll
    for (int k = 0; k < 64; k += 4) {
        a0 = fmaf(__shfl(m, k + 0), WT[k + 0][lane], a0);
        a1 = fmaf(__shfl(m, k + 1), WT[k + 1][lane], a1);
        a2 = fmaf(__shfl(m, k + 2), WT[k + 2][lane], a2);
        a3 = fmaf(__shfl(m, k + 3), WT[k + 3][lane], a3);
    }
    float r = (a0 + a1) + (a2 + a3);
    if (RMW) r += out[n * D + lane];
    out[n * D + lane] = r;
}

extern "C" void kernel_launch(void* const* d_in, const int* in_sizes, int n_in,
                              void* d_out, int out_size, void* d_ws, size_t ws_size,
                              hipStream_t stream)
{
    const float* feat_user = (const float*)d_in[0];
    const float* feat_item = (const float*)d_in[1];
    const float* W_f  = (const float*)d_in[2];
    const float* b_f  = (const float*)d_in[3];
    const float* W_r  = (const float*)d_in[4];
    const float* b_r  = (const float*)d_in[5];
    const float* W_rb = (const float*)d_in[6];
    const float* b_rb = (const float*)d_in[7];
    const int* src_f  = (const int*)d_in[8];
    const int* dst_f  = (const int*)d_in[9];
    const int* src_r  = (const int*)d_in[10];
    const int* dst_r  = (const int*)d_in[11];
    const int* src_rb = (const int*)d_in[12];
    const int* dst_rb = (const int*)d_in[13];
    float* out = (float*)d_out;

    const int NU = in_sizes[0] / D;   // 100000
    const int NI = in_sizes[1] / D;   // 100000 (== NU)
    const int E  = in_sizes[8];       // 1.6M per etype
    const int N  = NU;

    // Workspace (ints): hist/off/cur (3*NB*NSLICE each) + rp/cnt (3N each) + bkt/lst (3E each)
    const int M3 = 3 * NB * NSLICE;
    int* hist = (int*)d_ws;           // [3][NB][NSLICE]
    int* off  = hist + M3;
    int* cur  = off  + M3;
    int* rp   = cur  + M3;            // [3][N]
    int* cnt  = rp   + 3 * (size_t)N;
    int* bkt  = cnt  + 3 * (size_t)N; // [3][E] packed src|dl<<17
    int* lst  = bkt  + 3 * (size_t)E; // [3][E]

    hipMemsetAsync(hist, 0, (size_t)M3 * sizeof(int), stream);

    const dim3 blk(256);
    // etype order: 0=follows(dst user), 1=ratedby(dst user), 2=rates(dst item)
    bkt_hist<<<dim3(GRID_SCAT, 3), blk, 0, stream>>>(dst_f, dst_rb, dst_r, hist, E);
    bkt_scan<<<3, blk, 0, stream>>>(hist, off, cur);
    bkt_scatter<<<dim3(GRID_SCAT, 3), blk, 0, stream>>>(
        src_f, dst_f, src_rb, dst_rb, src_r, dst_r, cur, bkt, E, E);
    bkt_csr<<<dim3(NB, 3), blk, 0, stream>>>(off, bkt, rp, cnt, lst, N, E);

    int* rp_f  = rp;            int* cnt_f  = cnt;            int* lst_f  = lst;
    int* rp_rb = rp + N;        int* cnt_rb = cnt + N;        int* lst_rb = lst + E;
    int* rp_r  = rp + 2 * N;    int* cnt_r  = cnt + 2 * N;    int* lst_r  = lst + 2 * (size_t)E;

    const int gblk = (N + 3) / 4;
    // users: follows (store), then ratedby (RMW) -> cross-etype sum
    gather_proj<false><<<gblk, blk, 0, stream>>>(
        feat_user, rp_f, cnt_f, lst_f, W_f, b_f, out, NU);
    gather_proj<true><<<gblk, blk, 0, stream>>>(
        feat_item, rp_rb, cnt_rb, lst_rb, W_rb, b_rb, out, NU);
    // items: rates (store)
    gather_proj<false><<<gblk, blk, 0, stream>>>(
        feat_user, rp_r, cnt_r, lst_r, W_r, b_r, out + (size_t)NU * D, NI);
}

// Round 5
// 535.659 us; speedup vs baseline: 2.2248x; 2.2248x over previous
//
#include <hip/hip_runtime.h>

#define D 64
#define NPB_SHIFT 9                    // 512 dst nodes per bucket
#define NPB (1 << NPB_SHIFT)
#define NB 196                         // ceil(100000/512)
#define CHUNK 8192                     // edges per multisplit block (32 KB LDS stage)

// ---------- K1: per-(etype,bucket) histogram, LDS-aggregated ----------
__global__ __launch_bounds__(256) void bkt_hist(
    const int* __restrict__ d0, const int* __restrict__ d1, const int* __restrict__ d2,
    int* __restrict__ hist, int nE)    // hist[et][b]
{
    const int et = blockIdx.y;
    const int* dst = et == 0 ? d0 : (et == 1 ? d1 : d2);
    __shared__ int h[NB];
    for (int i = threadIdx.x; i < NB; i += 256) h[i] = 0;
    __syncthreads();
    for (int e = blockIdx.x * 256 + threadIdx.x; e < nE; e += gridDim.x * 256)
        atomicAdd(&h[dst[e] >> NPB_SHIFT], 1);
    __syncthreads();
    int* gh = hist + et * NB;
    for (int i = threadIdx.x; i < NB; i += 256)
        if (h[i]) atomicAdd(&gh[i], h[i]);
}

// ---------- K2: exclusive scan of hist[et][0..NB) -> off; init gcur ----------
__global__ __launch_bounds__(256) void bkt_scan(
    const int* __restrict__ hist, int* __restrict__ off, int* __restrict__ gcur)
{
    const int et = blockIdx.x;
    const int tid = threadIdx.x;
    const int v = tid < NB ? hist[et * NB + tid] : 0;
    int inc = v;
#pragma unroll
    for (int of = 1; of < 64; of <<= 1) {
        int t = __shfl_up(inc, of);
        if ((tid & 63) >= of) inc += t;
    }
    __shared__ int ws[4];
    if ((tid & 63) == 63) ws[tid >> 6] = inc;
    __syncthreads();
    int woff = 0;
    for (int i = 0; i < (tid >> 6); ++i) woff += ws[i];
    const int excl = woff + inc - v;
    if (tid < NB) { off[et * NB + tid] = excl; gcur[et * NB + tid] = excl; }
}

// ---------- K3: LDS multisplit scatter into bucket regions ----------
__global__ __launch_bounds__(256) void bkt_multisplit(
    const int* __restrict__ s0, const int* __restrict__ d0,
    const int* __restrict__ s1, const int* __restrict__ d1,
    const int* __restrict__ s2, const int* __restrict__ d2,
    int* __restrict__ gcur, int* __restrict__ bkt, int nE, int E)
{
    const int et = blockIdx.y;
    const int* src = et == 0 ? s0 : (et == 1 ? s1 : s2);
    const int* dst = et == 0 ? d0 : (et == 1 ? d1 : d2);
    int* gc = gcur + et * NB;
    int* bk = bkt + (size_t)et * E;

    __shared__ int h[NB];      // per-bucket count in this chunk
    __shared__ int st[NB];     // chunk-local start (scan of h)
    __shared__ int cu[NB];     // placement cursor
    __shared__ int gb[NB];     // reserved global base
    __shared__ int ws[4];
    __shared__ int stage[CHUNK];

    const int tid = threadIdx.x;
    const int e0 = blockIdx.x * CHUNK;
    const int e1 = min(e0 + CHUNK, nE);

    for (int i = tid; i < NB; i += 256) h[i] = 0;
    __syncthreads();
    for (int e = e0 + tid; e < e1; e += 256)
        atomicAdd(&h[dst[e] >> NPB_SHIFT], 1);
    __syncthreads();

    // exclusive scan of h[0..NB) across 256 threads (one value each)
    const int v = tid < NB ? h[tid] : 0;
    int inc = v;
#pragma unroll
    for (int of = 1; of < 64; of <<= 1) {
        int t = __shfl_up(inc, of);
        if ((tid & 63) >= of) inc += t;
    }
    if ((tid & 63) == 63) ws[tid >> 6] = inc;
    __syncthreads();
    int woff = 0;
    for (int i = 0; i < (tid >> 6); ++i) woff += ws[i];
    const int excl = woff + inc - v;
    if (tid < NB) {
        st[tid] = excl;
        cu[tid] = excl;
        if (v > 0) gb[tid] = atomicAdd(&gc[tid], v);   // one reservation per (block,bucket)
    }
    __syncthreads();

    // place packed words into LDS, sorted by bucket
    for (int e = e0 + tid; e < e1; e += 256) {
        const int dd = dst[e];
        const int b = dd >> NPB_SHIFT;
        const int pos = atomicAdd(&cu[b], 1);
        stage[pos] = src[e] | ((dd & (NPB - 1)) << 17);  // src < 2^17, dl < 2^9
    }
    __syncthreads();

    // flush: each wave takes buckets round-robin; runs are contiguous in LDS and global
    const int wv = tid >> 6, ln = tid & 63;
    for (int b = wv; b < NB; b += 4) {
        const int cb = h[b];
        if (cb == 0) continue;
        const int base = st[b], g = gb[b];
        for (int i = ln; i < cb; i += 64)
            bk[g + i] = stage[base + i];
    }
}

// ---------- K4: per-bucket CSR finalize: hist -> scan -> place; emits cnt/rp/lst ----------
__global__ __launch_bounds__(256) void bkt_csr(
    const int* __restrict__ off, const int* __restrict__ bkt_all,
    int* __restrict__ rp_all, int* __restrict__ cnt_all, int* __restrict__ lst_all,
    int N, int E)
{
    const int et = blockIdx.y;
    const int b = blockIdx.x;
    const int* o = off + et * NB;
    const int* bk = bkt_all + (size_t)et * E;
    int* lst = lst_all + (size_t)et * E;
    int* rp  = rp_all  + (size_t)et * N;
    int* cnt = cnt_all + (size_t)et * N;
    const int A  = o[b];
    const int Bb = (b + 1 < NB) ? o[b + 1] : E;

    __shared__ int h[NPB];
    __shared__ int cu[NPB];
    __shared__ int ws2[4];
    for (int i = threadIdx.x; i < NPB; i += 256) h[i] = 0;
    __syncthreads();
    for (int i = A + threadIdx.x; i < Bb; i += 256)
        atomicAdd(&h[((unsigned)bk[i]) >> 17], 1);
    __syncthreads();

    const int tid = threadIdx.x;
    const int v0 = h[2 * tid], v1 = h[2 * tid + 1];
    const int tsum = v0 + v1;
    int inc = tsum;
#pragma unroll
    for (int of = 1; of < 64; of <<= 1) {
        int t = __shfl_up(inc, of);
        if ((tid & 63) >= of) inc += t;
    }
    if ((tid & 63) == 63) ws2[tid >> 6] = inc;
    __syncthreads();
    int woff = 0;
    for (int i = 0; i < (tid >> 6); ++i) woff += ws2[i];
    const int excl = woff + inc - tsum;
    cu[2 * tid] = excl;
    cu[2 * tid + 1] = excl + v0;
    const int n0 = b << NPB_SHIFT;
    if (n0 + 2 * tid < N)     { cnt[n0 + 2 * tid]     = v0; rp[n0 + 2 * tid]     = A + excl; }
    if (n0 + 2 * tid + 1 < N) { cnt[n0 + 2 * tid + 1] = v1; rp[n0 + 2 * tid + 1] = A + excl + v0; }
    __syncthreads();

    for (int i = A + threadIdx.x; i < Bb; i += 256) {
        const int w = bk[i];
        const int dl = ((unsigned)w) >> 17;
        const int pos = atomicAdd(&cu[dl], 1);
        lst[A + pos] = w & 0x1FFFF;
    }
}

// ---------- K5: per-dst gather + mean + fused projection (unchanged) ----------
template <bool RMW>
__global__ __launch_bounds__(256) void gather_proj(
    const float* __restrict__ feat, const int* __restrict__ rp,
    const int* __restrict__ cnt, const int* __restrict__ lst,
    const float* __restrict__ W, const float* __restrict__ bias,
    float* __restrict__ out, int N)
{
    __shared__ float WT[64][65];
    __shared__ float bs[64];
    for (int i = threadIdx.x; i < 4096; i += 256)
        WT[i & 63][i >> 6] = W[i];
    if (threadIdx.x < 64) bs[threadIdx.x] = bias[threadIdx.x];
    __syncthreads();

    const int lane = threadIdx.x & 63;
    const int n = blockIdx.x * 4 + (threadIdx.x >> 6);
    if (n >= N) return;

    const int deg = cnt[n];
    const int start = rp[n];
    float s0 = 0.0f, s1 = 0.0f;
    for (int base = 0; base < deg; base += 8) {
        int idx[8];
        float f[8];
#pragma unroll
        for (int j = 0; j < 8; ++j)
            idx[j] = (base + j < deg) ? lst[start + base + j] : -1;
#pragma unroll
        for (int j = 0; j < 8; ++j)
            f[j] = feat[(idx[j] < 0 ? 0 : idx[j]) * D + lane];
#pragma unroll
        for (int j = 0; j < 8; ++j) {
            const float v = idx[j] < 0 ? 0.0f : f[j];
            if (j & 1) s1 += v; else s0 += v;
        }
    }
    const float m = deg > 0 ? (s0 + s1) / (float)deg : 0.0f;

    float a0 = deg > 0 ? bs[lane] : 0.0f;
    float a1 = 0.0f, a2 = 0.0f, a3 = 0.0f;
#pragma unroll
    for (int k = 0; k < 64; k += 4) {
        a0 = fmaf(__shfl(m, k + 0), WT[k + 0][lane], a0);
        a1 = fmaf(__shfl(m, k + 1), WT[k + 1][lane], a1);
        a2 = fmaf(__shfl(m, k + 2), WT[k + 2][lane], a2);
        a3 = fmaf(__shfl(m, k + 3), WT[k + 3][lane], a3);
    }
    float r = (a0 + a1) + (a2 + a3);
    if (RMW) r += out[n * D + lane];
    out[n * D + lane] = r;
}

extern "C" void kernel_launch(void* const* d_in, const int* in_sizes, int n_in,
                              void* d_out, int out_size, void* d_ws, size_t ws_size,
                              hipStream_t stream)
{
    const float* feat_user = (const float*)d_in[0];
    const float* feat_item = (const float*)d_in[1];
    const float* W_f  = (const float*)d_in[2];
    const float* b_f  = (const float*)d_in[3];
    const float* W_r  = (const float*)d_in[4];
    const float* b_r  = (const float*)d_in[5];
    const float* W_rb = (const float*)d_in[6];
    const float* b_rb = (const float*)d_in[7];
    const int* src_f  = (const int*)d_in[8];
    const int* dst_f  = (const int*)d_in[9];
    const int* src_r  = (const int*)d_in[10];
    const int* dst_r  = (const int*)d_in[11];
    const int* src_rb = (const int*)d_in[12];
    const int* dst_rb = (const int*)d_in[13];
    float* out = (float*)d_out;

    const int NU = in_sizes[0] / D;   // 100000
    const int NI = in_sizes[1] / D;   // 100000 (== NU)
    const int E  = in_sizes[8];       // 1.6M per etype
    const int N  = NU;

    // Workspace (ints)
    int* hist = (int*)d_ws;           // [3][NB]
    int* off  = hist + 3 * NB;        // [3][NB]
    int* gcur = off  + 3 * NB;        // [3][NB]
    int* rp   = gcur + 3 * NB;        // [3][N]
    int* cnt  = rp   + 3 * (size_t)N;
    int* bkt  = cnt  + 3 * (size_t)N; // [3][E] packed src|dl<<17
    int* lst  = bkt  + 3 * (size_t)E; // [3][E]

    hipMemsetAsync(hist, 0, (size_t)3 * NB * sizeof(int), stream);

    const dim3 blk(256);
    // etype order: 0=follows(dst user), 1=ratedby(dst user), 2=rates(dst item)
    bkt_hist<<<dim3(256, 3), blk, 0, stream>>>(dst_f, dst_rb, dst_r, hist, E);
    bkt_scan<<<3, blk, 0, stream>>>(hist, off, gcur);
    const int nms = (E + CHUNK - 1) / CHUNK;   // 196 for 1.6M
    bkt_multisplit<<<dim3(nms, 3), blk, 0, stream>>>(
        src_f, dst_f, src_rb, dst_rb, src_r, dst_r, gcur, bkt, E, E);
    bkt_csr<<<dim3(NB, 3), blk, 0, stream>>>(off, bkt, rp, cnt, lst, N, E);

    int* rp_f  = rp;            int* cnt_f  = cnt;            int* lst_f  = lst;
    int* rp_rb = rp + N;        int* cnt_rb = cnt + N;        int* lst_rb = lst + E;
    int* rp_r  = rp + 2 * N;    int* cnt_r  = cnt + 2 * N;    int* lst_r  = lst + 2 * (size_t)E;

    const int gblk = (N + 3) / 4;
    // users: follows (store), then ratedby (RMW) -> cross-etype sum
    gather_proj<false><<<gblk, blk, 0, stream>>>(
        feat_user, rp_f, cnt_f, lst_f, W_f, b_f, out, NU);
    gather_proj<true><<<gblk, blk, 0, stream>>>(
        feat_item, rp_rb, cnt_rb, lst_rb, W_rb, b_rb, out, NU);
    // items: rates (store)
    gather_proj<false><<<gblk, blk, 0, stream>>>(
        feat_user, rp_r, cnt_r, lst_r, W_r, b_r, out + (size_t)NU * D, NI);
}